// Round 11
// baseline (111.202 us; speedup 1.0000x reference)
//
#include <hip/hip_runtime.h>
#include <hip/hip_bf16.h>

// InfoNCE fused: loss = (1/N) sum_i [ log(sum_j exp(sim_ij)) - sim_ii ]
// sim = (z1/||z1||)@(z2/||z2||)^T / tau.  logits=[pos, diag-masked row] with
// pos == sim_ii => lse over the FULL row (diagonal included).
//
// z1f = bf16(z1n * log2(e)/tau) so exp(sim) = exp2(MFMA output); values in
// [-29,29] in log2 domain -> raw v_exp_f32 (__builtin_amdgcn_exp2f), NOT libm.
//
// R11 vs R7 (best main 46.3 us): occupancy theory refuted in R10 (64% occ,
// same wall). Constant ~46% VALUBusy across all shapes = correlated stall ->
// L2-thrash theory: all 2048 blocks co-resident, id%8 XCD round-robin means
// every XCD's L2 sees all 32 column windows (4MB = L2 size) -> B loads go to
// L3 (~600+ cyc) > unroll-4 slack (~670 cyc marginal). Fix: XCD-aware 1D
// swizzle: XCD k handles only column windows 4k..4k+3 (256KB/XCD, L2-hot).
// Everything else identical to R7.

typedef __bf16  bf16x8 __attribute__((ext_vector_type(8)));
typedef __bf16  bf16x4 __attribute__((ext_vector_type(4)));
typedef float   f32x4  __attribute__((ext_vector_type(4)));

#if __has_builtin(__builtin_amdgcn_exp2f)
#define EXP2F(x) __builtin_amdgcn_exp2f(x)   // raw v_exp_f32
#else
#define EXP2F(x) exp2f(x)
#endif
#if __has_builtin(__builtin_amdgcn_logf)
#define LOG2F(x) __builtin_amdgcn_logf(x)    // raw v_log_f32
#else
#define LOG2F(x) log2f(x)
#endif

#define DDIM   64
#define TILEB  2048         // bytes per fragment-ordered 16-col tile
#define NSETS  4            // 16-row MFMA sets per wave (64 rows/wave)
#define NW     4            // waves per block
#define BM     (NW * NSETS * 16)   // 256 rows per block
#define CS     32           // column windows; XCD k owns windows 4k..4k+3

// ---------------------------------------------------------------- normalize
// One block per 16-row tile. Thread (r = tid>>4, c = tid&15) loads
// z[row, 4c..4c+4), reduces ||row|| over its 16-lane group, writes the 4
// bf16 values into fragment order:
//   byte off(tile) = (c>>3)*1024 + ((c>>1)&3)*256 + r*16 + (c&1)*8
// Same thread holds row i of both views -> posv[i] = dot(z1f_i, z2f_i)
// computed here (bf16-rounded, matches MFMA diagonal). Zeroes rowsum; block 0
// zeroes d_out (stream-ordered before finalize's atomics).
__global__ __launch_bounds__(256) void norm_frag_kernel(
    const float* __restrict__ z1, const float* __restrict__ z2,
    __hip_bfloat16* __restrict__ z1f, __hip_bfloat16* __restrict__ z2f,
    float* __restrict__ rowsum, float* __restrict__ posv,
    float* __restrict__ out, float scale1, int N)
{
    const int tid  = threadIdx.x;
    const int r    = tid >> 4, c = tid & 15;
    const int tile = blockIdx.x;
    const size_t row = (size_t)tile * 16 + r;
    const size_t off = (size_t)tile * TILEB
                     + ((c >> 3) << 10) + (((c >> 1) & 3) << 8)
                     + (r << 4) + ((c & 1) << 3);

    bf16x4 o1, o2;
    // z1 (scaled by log2(e)/tau)
    {
        float4 v = *(const float4*)(z1 + row * DDIM + c * 4);
        float ss = v.x*v.x + v.y*v.y + v.z*v.z + v.w*v.w;
        #pragma unroll
        for (int o = 8; o; o >>= 1) ss += __shfl_xor(ss, o);
        float inv = scale1 / fmaxf(sqrtf(ss), 1e-12f);
        o1 = (bf16x4){ __float2bfloat16(v.x*inv), __float2bfloat16(v.y*inv),
                       __float2bfloat16(v.z*inv), __float2bfloat16(v.w*inv) };
        *(bf16x4*)((char*)z1f + off) = o1;
    }
    // z2 (unit scale)
    {
        float4 v = *(const float4*)(z2 + row * DDIM + c * 4);
        float ss = v.x*v.x + v.y*v.y + v.z*v.z + v.w*v.w;
        #pragma unroll
        for (int o = 8; o; o >>= 1) ss += __shfl_xor(ss, o);
        float inv = 1.0f / fmaxf(sqrtf(ss), 1e-12f);
        o2 = (bf16x4){ __float2bfloat16(v.x*inv), __float2bfloat16(v.y*inv),
                       __float2bfloat16(v.z*inv), __float2bfloat16(v.w*inv) };
        *(bf16x4*)((char*)z2f + off) = o2;
    }

    // posv[row] = dot of the bf16-rounded rows (log2-domain positive logit)
    float p = (float)o1[0]*(float)o2[0] + (float)o1[1]*(float)o2[1]
            + (float)o1[2]*(float)o2[2] + (float)o1[3]*(float)o2[3];
    #pragma unroll
    for (int o = 8; o; o >>= 1) p += __shfl_xor(p, o);
    if (c == 0) posv[row] = p;

    if (tid < 16) rowsum[(size_t)tile * 16 + tid] = 0.f;
    if (tile == 0 && tid == 0) *out = 0.f;
}

// ---------------------------------------------------------------- main
// 1D grid of 2048 blocks. XCD-aware decode (dispatch round-robins id%8):
//   xcd = id&7, w = (id>>3)&3, stripe = id>>5
//   column window y = 4*xcd + w  -> per-XCD z2f footprint = 4*64KB = 256KB
__global__ __launch_bounds__(256, 4) void infonce_main_kernel(
    const __hip_bfloat16* __restrict__ z1f,
    const __hip_bfloat16* __restrict__ z2f,
    float* __restrict__ rowsum,    // fp32, atomic partial rowsums of 2^C
    int N)
{
    const int tid  = threadIdx.x;
    const int wave = tid >> 6;
    const int lane = tid & 63;
    const int q    = lane >> 4;
    const int l15  = lane & 15;

    const int id      = blockIdx.x;
    const int xcd     = id & 7;
    const int w       = (id >> 3) & 3;
    const int xstripe = id >> 5;
    const int ybx     = (xcd << 2) | w;      // column window 0..31

    const int colspan = N / CS;
    const int ntiles  = colspan >> 4;
    const int c0      = ybx * colspan;
    const int wr      = xstripe * BM + wave * (NSETS * 16);

    // A fragments for NSETS row-tiles (coalesced: fragment-ordered global)
    bf16x8 a0[NSETS], a1[NSETS];
    #pragma unroll
    for (int s = 0; s < NSETS; ++s) {
        const char* ab = (const char*)z1f + (size_t)((wr >> 4) + s) * TILEB + lane * 16;
        a0[s] = *(const bf16x8*)(ab);
        a1[s] = *(const bf16x8*)(ab + 1024);
    }

    float sum[NSETS * 4];
    #pragma unroll
    for (int k = 0; k < NSETS * 4; ++k) sum[k] = 0.f;

    const char* bptr = (const char*)z2f + (size_t)(c0 >> 4) * TILEB + lane * 16;
    const f32x4 kzero = {0.f, 0.f, 0.f, 0.f};

    #pragma unroll 4
    for (int t = 0; t < ntiles; ++t) {
        bf16x8 b0 = *(const bf16x8*)(bptr);
        bf16x8 b1 = *(const bf16x8*)(bptr + 1024);
        bptr += TILEB;
        #pragma unroll
        for (int s = 0; s < NSETS; ++s) {
            f32x4 acc = __builtin_amdgcn_mfma_f32_16x16x32_bf16(a0[s], b0, kzero, 0, 0, 0);
            acc = __builtin_amdgcn_mfma_f32_16x16x32_bf16(a1[s], b1, acc, 0, 0, 0);
            sum[s * 4 + 0] += EXP2F(acc[0]);
            sum[s * 4 + 1] += EXP2F(acc[1]);
            sum[s * 4 + 2] += EXP2F(acc[2]);
            sum[s * 4 + 3] += EXP2F(acc[3]);
        }
    }

    // reduce each row-sum across the 16 lanes of the quad, then atomics
    #pragma unroll
    for (int k = 0; k < NSETS * 4; ++k) {
        float v = sum[k];
        #pragma unroll
        for (int o = 1; o < 16; o <<= 1) v += __shfl_xor(v, o);
        sum[k] = v;
    }
    if (l15 == 0) {
        #pragma unroll
        for (int s = 0; s < NSETS; ++s)
            #pragma unroll
            for (int i = 0; i < 4; ++i)
                atomicAdd(&rowsum[wr + s * 16 + q * 4 + i], sum[s * 4 + i]);
    }
}

// ---------------------------------------------------------------- finalize
// 64 blocks x 256 threads: thread t handles one row.
__global__ __launch_bounds__(256) void finalize_kernel(
    const float* __restrict__ rowsum, const float* __restrict__ posv,
    float* __restrict__ out, int N)
{
    int row = blockIdx.x * 256 + threadIdx.x;
    float acc = (LOG2F(rowsum[row]) - posv[row]) * (0.69314718055994531f / (float)N);
    #pragma unroll
    for (int o = 32; o; o >>= 1) acc += __shfl_xor(acc, o);
    if ((threadIdx.x & 63) == 0) atomicAdd(out, acc);
}

// ---------------------------------------------------------------- launch
extern "C" void kernel_launch(void* const* d_in, const int* in_sizes, int n_in,
                              void* d_out, int out_size, void* d_ws, size_t ws_size,
                              hipStream_t stream)
{
    const float* z1 = (const float*)d_in[0];
    const float* z2 = (const float*)d_in[1];
    const int N = in_sizes[0] / DDIM;   // 16384

    char* ws = (char*)d_ws;
    __hip_bfloat16* z1f = (__hip_bfloat16*)ws;                  // N*128 B (2 MB)
    __hip_bfloat16* z2f = z1f + (size_t)N * DDIM;               // N*128 B (2 MB)
    float* rowsum = (float*)(ws + 2 * (size_t)N * DDIM * 2);    // N*4 B
    float* posv   = rowsum + N;                                 // N*4 B

    const float kScale = 28.853900817779268f;   // log2(e) / 0.05

    norm_frag_kernel<<<N / 16, 256, 0, stream>>>(z1, z2, z1f, z2f, rowsum,
                                                 posv, (float*)d_out, kScale, N);

    // 1D grid: (N/BM) * CS = 64 * 32 = 2048 blocks, XCD-decoded in-kernel
    infonce_main_kernel<<<(N / BM) * CS, NW * 64, 0, stream>>>(z1f, z2f, rowsum, N);

    finalize_kernel<<<N / 256, 256, 0, stream>>>(rowsum, posv, (float*)d_out, N);
}

// Round 12
// 109.796 us; speedup vs baseline: 1.0128x; 1.0128x over previous
//
#include <hip/hip_runtime.h>
#include <hip/hip_bf16.h>

// InfoNCE fused: loss = (1/N) sum_i [ log(sum_j exp(sim_ij)) - sim_ii ]
// sim = (z1/||z1||)@(z2/||z2||)^T / tau.  logits=[pos, diag-masked row] with
// pos == sim_ii => lse over the FULL row (diagonal included).
//
// z1f = bf16(z1n * log2(e)/tau) so exp(sim) = exp2(MFMA output); values in
// [-29,29] in log2 domain -> raw v_exp_f32 (__builtin_amdgcn_exp2f), NOT libm.
//
// R12: cycle accounting shows VALU (~22us) and MFMA (~16.6us) pipes running
// SERIALLY (wall 48.6 ~ sum + idle, not max): the per-set acc=mfma;exp2(acc)
// RAW dependency convoys every wave. Fix: cross-tile software pipeline --
// issue tile t's MFMAs (into acc_cur) then exp2 tile t-1's acc_prev (fully
// independent) -> both pipes busy simultaneously. Loads stay 1 tile ahead.
// Base = R7 (best main 46.3us): NSETS=4, NW=4, CS=32, (256,4).

typedef __bf16  bf16x8 __attribute__((ext_vector_type(8)));
typedef __bf16  bf16x4 __attribute__((ext_vector_type(4)));
typedef float   f32x4  __attribute__((ext_vector_type(4)));

#if __has_builtin(__builtin_amdgcn_exp2f)
#define EXP2F(x) __builtin_amdgcn_exp2f(x)   // raw v_exp_f32
#else
#define EXP2F(x) exp2f(x)
#endif
#if __has_builtin(__builtin_amdgcn_logf)
#define LOG2F(x) __builtin_amdgcn_logf(x)    // raw v_log_f32
#else
#define LOG2F(x) log2f(x)
#endif

#define DDIM   64
#define TILEB  2048         // bytes per fragment-ordered 16-col tile
#define NSETS  4            // 16-row MFMA sets per wave (64 rows/wave)
#define NW     4            // waves per block
#define BM     (NW * NSETS * 16)   // 256 rows per block
#define CS     32           // column splits -> grid (64,32) = 2048 blocks

// ---------------------------------------------------------------- normalize
// One block per 16-row tile. Thread (r = tid>>4, c = tid&15) loads
// z[row, 4c..4c+4), reduces ||row|| over its 16-lane group, writes the 4
// bf16 values into fragment order:
//   byte off(tile) = (c>>3)*1024 + ((c>>1)&3)*256 + r*16 + (c&1)*8
// Same thread holds row i of both views -> posv[i] = dot(z1f_i, z2f_i)
// computed here (bf16-rounded, matches MFMA diagonal). Zeroes rowsum; block 0
// zeroes d_out (stream-ordered before finalize's atomics).
__global__ __launch_bounds__(256) void norm_frag_kernel(
    const float* __restrict__ z1, const float* __restrict__ z2,
    __hip_bfloat16* __restrict__ z1f, __hip_bfloat16* __restrict__ z2f,
    float* __restrict__ rowsum, float* __restrict__ posv,
    float* __restrict__ out, float scale1, int N)
{
    const int tid  = threadIdx.x;
    const int r    = tid >> 4, c = tid & 15;
    const int tile = blockIdx.x;
    const size_t row = (size_t)tile * 16 + r;
    const size_t off = (size_t)tile * TILEB
                     + ((c >> 3) << 10) + (((c >> 1) & 3) << 8)
                     + (r << 4) + ((c & 1) << 3);

    bf16x4 o1, o2;
    // z1 (scaled by log2(e)/tau)
    {
        float4 v = *(const float4*)(z1 + row * DDIM + c * 4);
        float ss = v.x*v.x + v.y*v.y + v.z*v.z + v.w*v.w;
        #pragma unroll
        for (int o = 8; o; o >>= 1) ss += __shfl_xor(ss, o);
        float inv = scale1 / fmaxf(sqrtf(ss), 1e-12f);
        o1 = (bf16x4){ __float2bfloat16(v.x*inv), __float2bfloat16(v.y*inv),
                       __float2bfloat16(v.z*inv), __float2bfloat16(v.w*inv) };
        *(bf16x4*)((char*)z1f + off) = o1;
    }
    // z2 (unit scale)
    {
        float4 v = *(const float4*)(z2 + row * DDIM + c * 4);
        float ss = v.x*v.x + v.y*v.y + v.z*v.z + v.w*v.w;
        #pragma unroll
        for (int o = 8; o; o >>= 1) ss += __shfl_xor(ss, o);
        float inv = 1.0f / fmaxf(sqrtf(ss), 1e-12f);
        o2 = (bf16x4){ __float2bfloat16(v.x*inv), __float2bfloat16(v.y*inv),
                       __float2bfloat16(v.z*inv), __float2bfloat16(v.w*inv) };
        *(bf16x4*)((char*)z2f + off) = o2;
    }

    // posv[row] = dot of the bf16-rounded rows (log2-domain positive logit)
    float p = (float)o1[0]*(float)o2[0] + (float)o1[1]*(float)o2[1]
            + (float)o1[2]*(float)o2[2] + (float)o1[3]*(float)o2[3];
    #pragma unroll
    for (int o = 8; o; o >>= 1) p += __shfl_xor(p, o);
    if (c == 0) posv[row] = p;

    if (tid < 16) rowsum[(size_t)tile * 16 + tid] = 0.f;
    if (tile == 0 && tid == 0) *out = 0.f;
}

// ---------------------------------------------------------------- main
__global__ __launch_bounds__(256, 4) void infonce_main_kernel(
    const __hip_bfloat16* __restrict__ z1f,
    const __hip_bfloat16* __restrict__ z2f,
    float* __restrict__ rowsum,    // fp32, atomic partial rowsums of 2^C
    int N)
{
    const int tid  = threadIdx.x;
    const int wave = tid >> 6;
    const int lane = tid & 63;
    const int q    = lane >> 4;
    const int l15  = lane & 15;

    const int colspan = N / CS;
    const int ntiles  = colspan >> 4;
    const int c0      = blockIdx.y * colspan;
    const int wr      = blockIdx.x * BM + wave * (NSETS * 16);

    // A fragments for NSETS row-tiles (coalesced: fragment-ordered global)
    bf16x8 a0[NSETS], a1[NSETS];
    #pragma unroll
    for (int s = 0; s < NSETS; ++s) {
        const char* ab = (const char*)z1f + (size_t)((wr >> 4) + s) * TILEB + lane * 16;
        a0[s] = *(const bf16x8*)(ab);
        a1[s] = *(const bf16x8*)(ab + 1024);
    }

    float sum[NSETS * 4];
    #pragma unroll
    for (int k = 0; k < NSETS * 4; ++k) sum[k] = 0.f;

    const char* bptr = (const char*)z2f + (size_t)(c0 >> 4) * TILEB + lane * 16;
    const f32x4 kzero = {0.f, 0.f, 0.f, 0.f};

    // ---- cross-tile software pipeline ----
    // b_cur holds tile t's B fragments; acc_prev holds tile t-1's MFMA
    // results. Body: issue loads(t+1); issue MFMAs(t) -> acc_cur (MFMA pipe);
    // exp2-accumulate acc_prev (VALU pipe, independent of acc_cur) -> overlap.
    bf16x8 b0c = *(const bf16x8*)(bptr);
    bf16x8 b1c = *(const bf16x8*)(bptr + 1024);
    bptr += TILEB;

    f32x4 accp[NSETS];
    #pragma unroll
    for (int s = 0; s < NSETS; ++s) {
        f32x4 t0 = __builtin_amdgcn_mfma_f32_16x16x32_bf16(a0[s], b0c, kzero, 0, 0, 0);
        accp[s]  = __builtin_amdgcn_mfma_f32_16x16x32_bf16(a1[s], b1c, t0, 0, 0, 0);
    }

    for (int t = 1; t < ntiles; ++t) {
        // loads for tile t (used by NEXT iteration's MFMAs via b_cur swap)
        bf16x8 b0n = *(const bf16x8*)(bptr);
        bf16x8 b1n = *(const bf16x8*)(bptr + 1024);
        bptr += TILEB;

        // MFMAs for tile t use b0n/b1n? No -- they use the values loaded one
        // iteration ago is unnecessary here: b0n was just issued; but the
        // exp2 burst below gives ~160 cyc of cover before acc_cur's MFMAs
        // actually need the data at issue time. Order: exp2(prev) AFTER the
        // MFMA issues so the MFMA pipe is filled first.
        f32x4 accc[NSETS];
        #pragma unroll
        for (int s = 0; s < NSETS; ++s) {
            f32x4 t0 = __builtin_amdgcn_mfma_f32_16x16x32_bf16(a0[s], b0c, kzero, 0, 0, 0);
            accc[s]  = __builtin_amdgcn_mfma_f32_16x16x32_bf16(a1[s], b1c, t0, 0, 0, 0);
        }

        // VALU burst on tile t-1's results -- independent of accc
        #pragma unroll
        for (int s = 0; s < NSETS; ++s) {
            sum[s * 4 + 0] += EXP2F(accp[s][0]);
            sum[s * 4 + 1] += EXP2F(accp[s][1]);
            sum[s * 4 + 2] += EXP2F(accp[s][2]);
            sum[s * 4 + 3] += EXP2F(accp[s][3]);
        }

        #pragma unroll
        for (int s = 0; s < NSETS; ++s) accp[s] = accc[s];
        b0c = b0n; b1c = b1n;
    }

    // epilogue: exp2 of the last tile's accumulators
    #pragma unroll
    for (int s = 0; s < NSETS; ++s) {
        sum[s * 4 + 0] += EXP2F(accp[s][0]);
        sum[s * 4 + 1] += EXP2F(accp[s][1]);
        sum[s * 4 + 2] += EXP2F(accp[s][2]);
        sum[s * 4 + 3] += EXP2F(accp[s][3]);
    }

    // reduce each row-sum across the 16 lanes of the quad, then atomics
    #pragma unroll
    for (int k = 0; k < NSETS * 4; ++k) {
        float v = sum[k];
        #pragma unroll
        for (int o = 1; o < 16; o <<= 1) v += __shfl_xor(v, o);
        sum[k] = v;
    }
    if (l15 == 0) {
        #pragma unroll
        for (int s = 0; s < NSETS; ++s)
            #pragma unroll
            for (int i = 0; i < 4; ++i)
                atomicAdd(&rowsum[wr + s * 16 + q * 4 + i], sum[s * 4 + i]);
    }
}

// ---------------------------------------------------------------- finalize
// 64 blocks x 256 threads: thread t handles one row.
__global__ __launch_bounds__(256) void finalize_kernel(
    const float* __restrict__ rowsum, const float* __restrict__ posv,
    float* __restrict__ out, int N)
{
    int row = blockIdx.x * 256 + threadIdx.x;
    float acc = (LOG2F(rowsum[row]) - posv[row]) * (0.69314718055994531f / (float)N);
    #pragma unroll
    for (int o = 32; o; o >>= 1) acc += __shfl_xor(acc, o);
    if ((threadIdx.x & 63) == 0) atomicAdd(out, acc);
}

// ---------------------------------------------------------------- launch
extern "C" void kernel_launch(void* const* d_in, const int* in_sizes, int n_in,
                              void* d_out, int out_size, void* d_ws, size_t ws_size,
                              hipStream_t stream)
{
    const float* z1 = (const float*)d_in[0];
    const float* z2 = (const float*)d_in[1];
    const int N = in_sizes[0] / DDIM;   // 16384

    char* ws = (char*)d_ws;
    __hip_bfloat16* z1f = (__hip_bfloat16*)ws;                  // N*128 B (2 MB)
    __hip_bfloat16* z2f = z1f + (size_t)N * DDIM;               // N*128 B (2 MB)
    float* rowsum = (float*)(ws + 2 * (size_t)N * DDIM * 2);    // N*4 B
    float* posv   = rowsum + N;                                 // N*4 B

    const float kScale = 28.853900817779268f;   // log2(e) / 0.05

    norm_frag_kernel<<<N / 16, 256, 0, stream>>>(z1, z2, z1f, z2f, rowsum,
                                                 posv, (float*)d_out, kScale, N);

    dim3 grid(N / BM, CS);
    infonce_main_kernel<<<grid, NW * 64, 0, stream>>>(z1f, z2f, rowsum, N);

    finalize_kernel<<<N / 256, 256, 0, stream>>>(rowsum, posv, (float*)d_out, N);
}